// Round 11
// baseline (204.897 us; speedup 1.0000x reference)
//
#include <hip/hip_runtime.h>
#include <hip/hip_bf16.h>

#define S_LEN 8192
#define DM    1024
#define DK    128
#define KSTR  136    // K LDS row stride (shorts): 2-way max bank aliasing
#define VSTR  72     // Vt LDS row stride (shorts)
#define PSTR2 72     // P LDS row stride (shorts)
#define SLOTD 1056   // dwords per partial slot: m[16] l[16] fp32 + O[16*128] fp16

typedef __attribute__((ext_vector_type(8))) short bf16x8;
typedef __attribute__((ext_vector_type(8))) _Float16 f16x8;
typedef __attribute__((ext_vector_type(4))) float f32x4;

__device__ __forceinline__ f32x4 mfma16(bf16x8 a, bf16x8 b, f32x4 c) {
    return __builtin_amdgcn_mfma_f32_16x16x32_bf16(a, b, c, 0, 0, 0);
}

// fp32 -> bf16 (RNE)
__device__ __forceinline__ ushort f2bf(float f) {
    unsigned u = __builtin_bit_cast(unsigned, f);
    u += 0x7FFFu + ((u >> 16) & 1u);
    return (ushort)(u >> 16);
}

__device__ __forceinline__ ushort f2h(float f) {
    return __builtin_bit_cast(ushort, (_Float16)f);
}

// ---------------------------------------------------------------------------
// Projection GEMM (fp16 MFMA): C[8192x384] = X[8192x1024] @ W^T.
// Stages fp32 -> fp16 inline (float4 load + cvt + ds_write_b64): the separate
// convert pass (50 MB traffic + launch) is eliminated; X re-reads hit L3.
// BM=64, grid (128,3) = 384 blocks. 4 waves, each 32x64 (2x4 accs).
// ---------------------------------------------------------------------------
__global__ __launch_bounds__(256)
void proj_gemm_kernel(const float* __restrict__ Xf,
                      const float* __restrict__ Wq,
                      const float* __restrict__ Wk,
                      const float* __restrict__ Wv,
                      ushort* __restrict__ Qb,
                      ushort* __restrict__ Kb,
                      ushort* __restrict__ Vtb) {
    __shared__ _Float16 Ash[64 * 32];    // 4 KB
    __shared__ _Float16 Bsh[128 * 32];   // 8 KB

    const int tid  = threadIdx.x;
    const int lane = tid & 63;
    const int quad = lane >> 4;
    const int l15  = lane & 15;
    const int wv   = tid >> 6;
    const int wm   = wv & 1;    // m-half (32 rows)
    const int wn   = wv >> 1;   // n-half (64 cols)
    const int m0   = blockIdx.x * 64;
    const int nb   = blockIdx.y;
    const float* Wbase = (nb == 0) ? Wq : (nb == 1 ? Wk : Wv);

    f32x4 acc[2][4];
#pragma unroll
    for (int mi = 0; mi < 2; ++mi)
#pragma unroll
        for (int ni = 0; ni < 4; ++ni) acc[mi][ni] = (f32x4){0.f, 0.f, 0.f, 0.f};

    for (int kk = 0; kk < DM; kk += 32) {
        __syncthreads();
        // A: 64 rows x 8 float4 = 512 chunks; B: 128 rows x 8 = 1024; total 1536
#pragma unroll
        for (int s = tid; s < 1536; s += 256) {
            float4 v;
            _Float16* dst;
            if (s < 512) {
                const int row = s >> 3, sg = s & 7;
                v = *(const float4*)(Xf + (size_t)(m0 + row) * DM + kk + sg * 4);
                dst = Ash + row * 32 + sg * 4;
            } else {
                const int t = s - 512;
                const int row = t >> 3, sg = t & 7;
                v = *(const float4*)(Wbase + (size_t)row * DM + kk + sg * 4);
                dst = Bsh + row * 32 + sg * 4;
            }
            union { _Float16 h[4]; uint2 u; } p;
            p.h[0] = (_Float16)v.x; p.h[1] = (_Float16)v.y;
            p.h[2] = (_Float16)v.z; p.h[3] = (_Float16)v.w;
            *(uint2*)dst = p.u;
        }
        __syncthreads();

        f16x8 af[2], bf[4];
#pragma unroll
        for (int t = 0; t < 2; ++t)
            af[t] = *(const f16x8*)(Ash + (wm * 32 + t * 16 + l15) * 32 + quad * 8);
#pragma unroll
        for (int t = 0; t < 4; ++t)
            bf[t] = *(const f16x8*)(Bsh + (wn * 64 + t * 16 + l15) * 32 + quad * 8);
#pragma unroll
        for (int mi = 0; mi < 2; ++mi)
#pragma unroll
            for (int ni = 0; ni < 4; ++ni)
                acc[mi][ni] = __builtin_amdgcn_mfma_f32_16x16x32_f16(af[mi], bf[ni], acc[mi][ni], 0, 0, 0);
    }

    if (nb == 2) {
#pragma unroll
        for (int mi = 0; mi < 2; ++mi)
#pragma unroll
            for (int ni = 0; ni < 4; ++ni) {
                const int n = wn * 64 + ni * 16 + l15;
                const int m = m0 + wm * 32 + mi * 16 + quad * 4;
                union { ushort h[4]; uint2 u; } p;
#pragma unroll
                for (int r = 0; r < 4; ++r) p.h[r] = f2bf(acc[mi][ni][r]);
                *(uint2*)(Vtb + (size_t)n * S_LEN + m) = p.u;
            }
    } else {
        ushort* Ob = (nb == 0) ? Qb : Kb;
        const float sc = (nb == 0) ? 0.088388347648318447f * 1.4426950408889634f : 1.0f;
#pragma unroll
        for (int mi = 0; mi < 2; ++mi)
#pragma unroll
            for (int ni = 0; ni < 4; ++ni) {
                const int n = wn * 64 + ni * 16 + l15;
#pragma unroll
                for (int r = 0; r < 4; ++r) {
                    const int m = m0 + wm * 32 + mi * 16 + quad * 4 + r;
                    Ob[(size_t)m * DK + n] = f2bf(acc[mi][ni][r] * sc);
                }
            }
    }
}

// ---------------------------------------------------------------------------
// Flash attention partials, LDS-staged + register prefetch + sum-via-MFMA.
// Heavy-first (LPT) ordering: b = 575 - blockIdx.x launches the largest-work
// blocks first (work per block ranges 1..16 tiles) -> shorter makespan tail.
// ---------------------------------------------------------------------------
__global__ __launch_bounds__(256, 3)
void flash_partial_kernel(const ushort* __restrict__ Qg,
                          const ushort* __restrict__ Kg,
                          const ushort* __restrict__ Vtg,
                          float* __restrict__ Part) {
    __shared__ __align__(16) ushort Ks [64 * KSTR];      // 17408 B
    __shared__ __align__(16) ushort Vts[128 * VSTR];     // 18432 B
    __shared__ __align__(16) ushort PlA[4 * 16 * PSTR2]; // 9216 B

    // decode (qb, chunk): group g has 16*(g+1) blocks, cumulative 8g(g+1)
    const int b = 575 - (int)blockIdx.x;   // heavy-first
    int g = 0;
    while (b >= 8 * (g + 1) * (g + 2)) ++g;
    const int idx   = b - 8 * g * (g + 1);
    const int qb    = 16 * g + idx / (g + 1);
    const int chunk = idx % (g + 1);
    const int nkt   = qb + 1;
    const int kt_lo = chunk * nkt / (g + 1);
    const int kt_hi = (chunk + 1) * nkt / (g + 1);

    const int tid  = threadIdx.x;
    const int wv   = tid >> 6;
    const int lane = tid & 63;
    const int quad = lane >> 4;
    const int l15  = lane & 15;
    const int q0w  = qb * 64 + wv * 16;
    ushort* Pl = PlA + wv * 16 * PSTR2;

    // Q fragments (A layout), resident
    bf16x8 qf[4];
    {
        const ushort* qrow = Qg + (size_t)(q0w + l15) * DK + quad * 8;
#pragma unroll
        for (int kc = 0; kc < 4; ++kc) qf[kc] = *(const bf16x8*)(qrow + kc * 32);
    }

    const bf16x8 ones = {(short)0x3F80, (short)0x3F80, (short)0x3F80, (short)0x3F80,
                         (short)0x3F80, (short)0x3F80, (short)0x3F80, (short)0x3F80};

    float m_[4], l_[4];
#pragma unroll
    for (int r = 0; r < 4; ++r) { m_[r] = -__builtin_inff(); l_[r] = 0.f; }
    f32x4 acc[8];
#pragma unroll
    for (int d = 0; d < 8; ++d) acc[d] = (f32x4){0.f, 0.f, 0.f, 0.f};

    bf16x8 stg[8];
#define LOAD_TILE(K0)                                                          \
    {                                                                          \
        const int k0_ = (K0);                                                  \
        _Pragma("unroll")                                                      \
        for (int i = 0; i < 8; ++i) {                                          \
            const int c = tid + (i << 8);                                      \
            if (c < 1024) {                                                    \
                const int row = c >> 4, ch = c & 15;                           \
                stg[i] = *(const bf16x8*)(Kg + (size_t)(k0_ + row) * DK + ch * 8); \
            } else {                                                           \
                const int cc = c - 1024;                                       \
                const int row = cc >> 3, ch = cc & 7;                          \
                stg[i] = *(const bf16x8*)(Vtg + (size_t)row * S_LEN + k0_ + ch * 8); \
            }                                                                  \
        }                                                                      \
    }

    LOAD_TILE(kt_lo * 64)

    for (int kt = kt_lo; kt < kt_hi; ++kt) {
        const int k0 = kt * 64;

        __syncthreads();   // previous tile's frag reads complete
#pragma unroll
        for (int i = 0; i < 8; ++i) {
            const int c = tid + (i << 8);
            if (c < 1024) {
                const int row = c >> 4, ch = c & 15;
                *(bf16x8*)(Ks + row * KSTR + ch * 8) = stg[i];
            } else {
                const int cc = c - 1024;
                const int row = cc >> 3, ch = cc & 7;
                *(bf16x8*)(Vts + row * VSTR + ch * 8) = stg[i];
            }
        }
        if (kt + 1 < kt_hi) LOAD_TILE((kt + 1) * 64)   // prefetch into regs
        __syncthreads();   // staging visible to all waves

        // ---- S = Q K^T (16 x 64), B-frags from LDS ----
        f32x4 Sr[4];
#pragma unroll
        for (int nb = 0; nb < 4; ++nb) {
            Sr[nb] = (f32x4){0.f, 0.f, 0.f, 0.f};
            const ushort* kb = Ks + (nb * 16 + l15) * KSTR + quad * 8;
#pragma unroll
            for (int kc = 0; kc < 4; ++kc)
                Sr[nb] = mfma16(qf[kc], *(const bf16x8*)(kb + kc * 32), Sr[nb]);
        }

        // ---- causal mask (diagonal tile only) ----
        if (k0 + 63 > q0w) {
#pragma unroll
            for (int nb = 0; nb < 4; ++nb) {
                const int kg = k0 + nb * 16 + l15;
#pragma unroll
                for (int r = 0; r < 4; ++r)
                    if (kg > q0w + quad * 4 + r) Sr[nb][r] = -__builtin_inff();
            }
        }

        // ---- online softmax: row max via shuffles, P to LDS ----
        float al[4];
#pragma unroll
        for (int r = 0; r < 4; ++r) {
            float v = m_[r];
#pragma unroll
            for (int nb = 0; nb < 4; ++nb) v = fmaxf(v, Sr[nb][r]);
            v = fmaxf(v, __shfl_xor(v, 1));
            v = fmaxf(v, __shfl_xor(v, 2));
            v = fmaxf(v, __shfl_xor(v, 4));
            v = fmaxf(v, __shfl_xor(v, 8));
            al[r] = exp2f(m_[r] - v);
            m_[r] = v;
        }
#pragma unroll
        for (int nb = 0; nb < 4; ++nb) {
#pragma unroll
            for (int r = 0; r < 4; ++r) {
                const float p = exp2f(Sr[nb][r] - m_[r]);
                Pl[(quad * 4 + r) * PSTR2 + nb * 16 + l15] = f2bf(p);
            }
        }
#pragma unroll
        for (int d = 0; d < 8; ++d)
#pragma unroll
            for (int r = 0; r < 4; ++r) acc[d][r] *= al[r];

        // ---- O += P V; row-sum of P via MFMA with B=ones ----
        f32x4 sacc = (f32x4){0.f, 0.f, 0.f, 0.f};
#pragma unroll
        for (int kcp = 0; kcp < 2; ++kcp) {
            const bf16x8 pf = *(const bf16x8*)(Pl + l15 * PSTR2 + kcp * 32 + quad * 8);
            sacc = mfma16(pf, ones, sacc);
#pragma unroll
            for (int db = 0; db < 8; ++db) {
                const bf16x8 vf = *(const bf16x8*)(Vts + (db * 16 + l15) * VSTR + kcp * 32 + quad * 8);
                acc[db] = mfma16(pf, vf, acc[db]);
            }
        }
#pragma unroll
        for (int r = 0; r < 4; ++r) l_[r] = l_[r] * al[r] + sacc[r];
    }
#undef LOAD_TILE

    // ---- write partial slot (wave-private, no merge needed) ----
    const int qt16 = qb * 4 + wv;
    float* slot = Part + (size_t)(qt16 * 8 + chunk) * SLOTD;
    if (l15 == 0) {
#pragma unroll
        for (int r = 0; r < 4; ++r) {
            slot[quad * 4 + r]      = m_[r];
            slot[16 + quad * 4 + r] = l_[r];
        }
    }
    // O as fp16: pair lanes (l15 even/odd -> dims d, d+1) into one dword
    uint* slotO = (uint*)(slot + 32);
#pragma unroll
    for (int d = 0; d < 8; ++d)
#pragma unroll
        for (int r = 0; r < 4; ++r) {
            const float v  = acc[d][r];
            const float vp = __shfl_xor(v, 1);
            if ((l15 & 1) == 0) {
                const int row = quad * 4 + r;
                const uint u = (uint)f2h(v) | ((uint)f2h(vp) << 16);
                slotO[(row * 128 + d * 16 + l15) >> 1] = u;
            }
        }
}

// ---------------------------------------------------------------------------
// Merge <=8 partials per 16-row q-tile, normalize, write output.
// 256 thr/block, rescale factors precomputed in LDS, vectorized I/O.
// ---------------------------------------------------------------------------
__global__ __launch_bounds__(256)
void flash_merge_kernel(const float* __restrict__ Part, float* __restrict__ Out) {
    __shared__ float Ms[16], Ls[16];
    __shared__ float Sc[8][16];
    const int qt = blockIdx.x;
    const int q0 = qt * 16;
    const int P  = (qt >> 6) + 1;
    const int tid = threadIdx.x;
    const float* base = Part + (size_t)qt * 8 * SLOTD;

    if (tid < 16) {
        float M = -__builtin_inff();
        for (int p = 0; p < P; ++p) M = fmaxf(M, base[p * SLOTD + tid]);
        float L = 0.f;
        for (int p = 0; p < P; ++p)
            L += base[p * SLOTD + 16 + tid] * exp2f(base[p * SLOTD + tid] - M);
        Ms[tid] = M; Ls[tid] = L;
    }
    __syncthreads();
    if (tid < 128) {
        const int p = tid >> 4, row = tid & 15;
        Sc[p][row] = (p < P) ? exp2f(base[p * SLOTD + row] - Ms[row]) : 0.f;
    }
    __syncthreads();

    // 16 rows x 64 dword-pairs (2 fp16 cols each) = 1024 items, 4 per thread
#pragma unroll
    for (int j = tid; j < 1024; j += 256) {
        const int row = j >> 6, c2 = j & 63;
        float o0 = 0.f, o1 = 0.f;
        for (int p = 0; p < P; ++p) {
            const uint u = ((const uint*)(base + p * SLOTD + 32))[row * 64 + c2];
            const float sc = Sc[p][row];
            o0 += (float)__builtin_bit_cast(_Float16, (ushort)(u & 0xFFFF)) * sc;
            o1 += (float)__builtin_bit_cast(_Float16, (ushort)(u >> 16)) * sc;
        }
        const float inv = 1.0f / Ls[row];
        float2 o; o.x = o0 * inv; o.y = o1 * inv;
        *(float2*)(Out + (size_t)(q0 + row) * DK + c2 * 2) = o;
    }
}

extern "C" void kernel_launch(void* const* d_in, const int* in_sizes, int n_in,
                              void* d_out, int out_size, void* d_ws, size_t ws_size,
                              hipStream_t stream) {
    const float* X  = (const float*)d_in[0];
    const float* Wq = (const float*)d_in[1];
    const float* Wk = (const float*)d_in[2];
    const float* Wv = (const float*)d_in[3];
    ushort* ws  = (ushort*)d_ws;
    ushort* Qb  = ws;                          // 8192x128 bf16 (pre-scaled)
    ushort* Kb  = ws + (size_t)S_LEN * DK;     // 8192x128 bf16
    ushort* Vtb = ws + 2 * (size_t)S_LEN * DK; // 128x8192 bf16 (transposed)
    // Partials: 4096 slots * 4224 B = 16.5 MiB right after Q/K/Vt (22.8 MB total)
    float* Part = (float*)(ws + 3 * (size_t)S_LEN * DK);
    float* Out = (float*)d_out;

    proj_gemm_kernel<<<dim3(128, 3), 256, 0, stream>>>(X, Wq, Wk, Wv, Qb, Kb, Vtb);
    flash_partial_kernel<<<576, 256, 0, stream>>>(Qb, Kb, Vtb, Part);
    flash_merge_kernel<<<512, 256, 0, stream>>>(Part, Out);
}

// Round 12
// 179.599 us; speedup vs baseline: 1.1409x; 1.1409x over previous
//
#include <hip/hip_runtime.h>
#include <hip/hip_bf16.h>

#define S_LEN 8192
#define DM    1024
#define DK    128
#define KSTR  136    // K LDS row stride (shorts): 2-way max bank aliasing
#define VSTR  72     // Vt LDS row stride (shorts)
#define PSTR2 72     // P LDS row stride (shorts)
#define SLOTD 1056   // dwords per partial slot: m[16] l[16] fp32 + O[16*128] fp16

typedef __attribute__((ext_vector_type(8))) short bf16x8;
typedef __attribute__((ext_vector_type(8))) _Float16 f16x8;
typedef __attribute__((ext_vector_type(4))) float f32x4;

__device__ __forceinline__ f32x4 mfma16(bf16x8 a, bf16x8 b, f32x4 c) {
    return __builtin_amdgcn_mfma_f32_16x16x32_bf16(a, b, c, 0, 0, 0);
}

// fp32 -> bf16 (RNE)
__device__ __forceinline__ ushort f2bf(float f) {
    unsigned u = __builtin_bit_cast(unsigned, f);
    u += 0x7FFFu + ((u >> 16) & 1u);
    return (ushort)(u >> 16);
}

__device__ __forceinline__ ushort f2h(float f) {
    return __builtin_bit_cast(ushort, (_Float16)f);
}

// ---------------------------------------------------------------------------
// fp32 -> fp16 conversion of X (8192x1024) and Wq|Wk|Wv (each 128x1024).
// ---------------------------------------------------------------------------
__global__ __launch_bounds__(256, 1)
void convert_kernel(const float* __restrict__ X,
                    const float* __restrict__ Wq,
                    const float* __restrict__ Wk,
                    const float* __restrict__ Wv,
                    _Float16* __restrict__ Xh,
                    _Float16* __restrict__ Wh) {
    const int NX4 = S_LEN * DM / 4;
    const int NW4 = DK * DM / 4;
    const int total4 = NX4 + 3 * NW4;
    for (int i = blockIdx.x * 256 + threadIdx.x; i < total4; i += gridDim.x * 256) {
        const float4* src;
        _Float16* dst;
        int off;
        if (i < NX4) {
            src = (const float4*)X; dst = Xh; off = i;
        } else {
            const int w = i - NX4;
            const int which = w / NW4;
            off = w - which * NW4;
            src = (const float4*)(which == 0 ? Wq : (which == 1 ? Wk : Wv));
            dst = Wh + which * (DK * DM);
        }
        const float4 v = src[off];
        union { _Float16 h[4]; uint2 u; } p;
        p.h[0] = (_Float16)v.x; p.h[1] = (_Float16)v.y;
        p.h[2] = (_Float16)v.z; p.h[3] = (_Float16)v.w;
        *(uint2*)(dst + (size_t)off * 4) = p.u;
    }
}

// ---------------------------------------------------------------------------
// Projection GEMM (fp16 MFMA): C[8192x384] = Xh @ Wh^T.
// BM=32, grid (256,3) = 768 blocks -> 3 blocks/CU, 12 waves/CU (r11's inline-
// convert + 384-block variant was latency-starved: 80 us, all pipes idle).
// Staging via async global_load_lds width-16 (wave-contiguous LDS dests).
// Wave w: m-tile (w&1), n-half (w>>1); acc = 4 f32x4.
// ---------------------------------------------------------------------------
__global__ __launch_bounds__(256)
void proj_gemm_kernel(const _Float16* __restrict__ Xh,
                      const _Float16* __restrict__ Wh,
                      ushort* __restrict__ Qb,
                      ushort* __restrict__ Kb,
                      ushort* __restrict__ Vtb) {
    __shared__ _Float16 Ash[32 * 32];    // 2 KB
    __shared__ _Float16 Bsh[128 * 32];   // 8 KB

    const int tid  = threadIdx.x;
    const int lane = tid & 63;
    const int quad = lane >> 4;
    const int l15  = lane & 15;
    const int wv   = tid >> 6;
    const int wm   = wv & 1;    // m-tile (16 rows)
    const int wn   = wv >> 1;   // n-half (64 cols)
    const int m0   = blockIdx.x * 32;
    const int nb   = blockIdx.y;
    const _Float16* Wbase = Wh + nb * (DK * DM);

    f32x4 acc[4];
#pragma unroll
    for (int ni = 0; ni < 4; ++ni) acc[ni] = (f32x4){0.f, 0.f, 0.f, 0.f};

    for (int kk = 0; kk < DM; kk += 32) {
        __syncthreads();
        // A: 32 rows x 4 chunks = 128; B: 128 rows x 4 chunks = 512; total 640
        for (int s = tid; s < 640; s += 256) {
            if (s < 128) {
                const int row = s >> 2, sg = s & 3;
                __builtin_amdgcn_global_load_lds(
                    (const __attribute__((address_space(1))) void*)(Xh + (size_t)(m0 + row) * DM + kk + sg * 8),
                    (__attribute__((address_space(3))) void*)(Ash + s * 8), 16, 0, 0);
            } else {
                const int t = s - 128;
                const int row = t >> 2, sg = t & 3;
                __builtin_amdgcn_global_load_lds(
                    (const __attribute__((address_space(1))) void*)(Wbase + (size_t)row * DM + kk + sg * 8),
                    (__attribute__((address_space(3))) void*)(Bsh + t * 8), 16, 0, 0);
            }
        }
        __syncthreads();

        const f16x8 af = *(const f16x8*)(Ash + (wm * 16 + l15) * 32 + quad * 8);
        f16x8 bf[4];
#pragma unroll
        for (int t = 0; t < 4; ++t)
            bf[t] = *(const f16x8*)(Bsh + (wn * 64 + t * 16 + l15) * 32 + quad * 8);
#pragma unroll
        for (int ni = 0; ni < 4; ++ni)
            acc[ni] = __builtin_amdgcn_mfma_f32_16x16x32_f16(af, bf[ni], acc[ni], 0, 0, 0);
    }

    if (nb == 2) {
#pragma unroll
        for (int ni = 0; ni < 4; ++ni) {
            const int n = wn * 64 + ni * 16 + l15;
            const int m = m0 + wm * 16 + quad * 4;
            union { ushort h[4]; uint2 u; } p;
#pragma unroll
            for (int r = 0; r < 4; ++r) p.h[r] = f2bf(acc[ni][r]);
            *(uint2*)(Vtb + (size_t)n * S_LEN + m) = p.u;
        }
    } else {
        ushort* Ob = (nb == 0) ? Qb : Kb;
        const float sc = (nb == 0) ? 0.088388347648318447f * 1.4426950408889634f : 1.0f;
#pragma unroll
        for (int ni = 0; ni < 4; ++ni) {
            const int n = wn * 64 + ni * 16 + l15;
#pragma unroll
            for (int r = 0; r < 4; ++r) {
                const int m = m0 + wm * 16 + quad * 4 + r;
                Ob[(size_t)m * DK + n] = f2bf(acc[ni][r] * sc);
            }
        }
    }
}

// ---------------------------------------------------------------------------
// Flash attention partials, LDS-staged + register prefetch + sum-via-MFMA.
// Heavy-first (LPT) ordering for the 1..16-tile work spread.
// ---------------------------------------------------------------------------
__global__ __launch_bounds__(256, 3)
void flash_partial_kernel(const ushort* __restrict__ Qg,
                          const ushort* __restrict__ Kg,
                          const ushort* __restrict__ Vtg,
                          float* __restrict__ Part) {
    __shared__ __align__(16) ushort Ks [64 * KSTR];      // 17408 B
    __shared__ __align__(16) ushort Vts[128 * VSTR];     // 18432 B
    __shared__ __align__(16) ushort PlA[4 * 16 * PSTR2]; // 9216 B

    // decode (qb, chunk): group g has 16*(g+1) blocks, cumulative 8g(g+1)
    const int b = 575 - (int)blockIdx.x;   // heavy-first
    int g = 0;
    while (b >= 8 * (g + 1) * (g + 2)) ++g;
    const int idx   = b - 8 * g * (g + 1);
    const int qb    = 16 * g + idx / (g + 1);
    const int chunk = idx % (g + 1);
    const int nkt   = qb + 1;
    const int kt_lo = chunk * nkt / (g + 1);
    const int kt_hi = (chunk + 1) * nkt / (g + 1);

    const int tid  = threadIdx.x;
    const int wv   = tid >> 6;
    const int lane = tid & 63;
    const int quad = lane >> 4;
    const int l15  = lane & 15;
    const int q0w  = qb * 64 + wv * 16;
    ushort* Pl = PlA + wv * 16 * PSTR2;

    // Q fragments (A layout), resident
    bf16x8 qf[4];
    {
        const ushort* qrow = Qg + (size_t)(q0w + l15) * DK + quad * 8;
#pragma unroll
        for (int kc = 0; kc < 4; ++kc) qf[kc] = *(const bf16x8*)(qrow + kc * 32);
    }

    const bf16x8 ones = {(short)0x3F80, (short)0x3F80, (short)0x3F80, (short)0x3F80,
                         (short)0x3F80, (short)0x3F80, (short)0x3F80, (short)0x3F80};

    float m_[4], l_[4];
#pragma unroll
    for (int r = 0; r < 4; ++r) { m_[r] = -__builtin_inff(); l_[r] = 0.f; }
    f32x4 acc[8];
#pragma unroll
    for (int d = 0; d < 8; ++d) acc[d] = (f32x4){0.f, 0.f, 0.f, 0.f};

    bf16x8 stg[8];
#define LOAD_TILE(K0)                                                          \
    {                                                                          \
        const int k0_ = (K0);                                                  \
        _Pragma("unroll")                                                      \
        for (int i = 0; i < 8; ++i) {                                          \
            const int c = tid + (i << 8);                                      \
            if (c < 1024) {                                                    \
                const int row = c >> 4, ch = c & 15;                           \
                stg[i] = *(const bf16x8*)(Kg + (size_t)(k0_ + row) * DK + ch * 8); \
            } else {                                                           \
                const int cc = c - 1024;                                       \
                const int row = cc >> 3, ch = cc & 7;                          \
                stg[i] = *(const bf16x8*)(Vtg + (size_t)row * S_LEN + k0_ + ch * 8); \
            }                                                                  \
        }                                                                      \
    }

    LOAD_TILE(kt_lo * 64)

    for (int kt = kt_lo; kt < kt_hi; ++kt) {
        const int k0 = kt * 64;

        __syncthreads();   // previous tile's frag reads complete
#pragma unroll
        for (int i = 0; i < 8; ++i) {
            const int c = tid + (i << 8);
            if (c < 1024) {
                const int row = c >> 4, ch = c & 15;
                *(bf16x8*)(Ks + row * KSTR + ch * 8) = stg[i];
            } else {
                const int cc = c - 1024;
                const int row = cc >> 3, ch = cc & 7;
                *(bf16x8*)(Vts + row * VSTR + ch * 8) = stg[i];
            }
        }
        if (kt + 1 < kt_hi) LOAD_TILE((kt + 1) * 64)   // prefetch into regs
        __syncthreads();   // staging visible to all waves

        // ---- S = Q K^T (16 x 64), B-frags from LDS ----
        f32x4 Sr[4];
#pragma unroll
        for (int nb = 0; nb < 4; ++nb) {
            Sr[nb] = (f32x4){0.f, 0.f, 0.f, 0.f};
            const ushort* kb = Ks + (nb * 16 + l15) * KSTR + quad * 8;
#pragma unroll
            for (int kc = 0; kc < 4; ++kc)
                Sr[nb] = mfma16(qf[kc], *(const bf16x8*)(kb + kc * 32), Sr[nb]);
        }

        // ---- causal mask (diagonal tile only) ----
        if (k0 + 63 > q0w) {
#pragma unroll
            for (int nb = 0; nb < 4; ++nb) {
                const int kg = k0 + nb * 16 + l15;
#pragma unroll
                for (int r = 0; r < 4; ++r)
                    if (kg > q0w + quad * 4 + r) Sr[nb][r] = -__builtin_inff();
            }
        }

        // ---- online softmax: row max via shuffles, P to LDS ----
        float al[4];
#pragma unroll
        for (int r = 0; r < 4; ++r) {
            float v = m_[r];
#pragma unroll
            for (int nb = 0; nb < 4; ++nb) v = fmaxf(v, Sr[nb][r]);
            v = fmaxf(v, __shfl_xor(v, 1));
            v = fmaxf(v, __shfl_xor(v, 2));
            v = fmaxf(v, __shfl_xor(v, 4));
            v = fmaxf(v, __shfl_xor(v, 8));
            al[r] = exp2f(m_[r] - v);
            m_[r] = v;
        }
#pragma unroll
        for (int nb = 0; nb < 4; ++nb) {
#pragma unroll
            for (int r = 0; r < 4; ++r) {
                const float p = exp2f(Sr[nb][r] - m_[r]);
                Pl[(quad * 4 + r) * PSTR2 + nb * 16 + l15] = f2bf(p);
            }
        }
#pragma unroll
        for (int d = 0; d < 8; ++d)
#pragma unroll
            for (int r = 0; r < 4; ++r) acc[d][r] *= al[r];

        // ---- O += P V; row-sum of P via MFMA with B=ones ----
        f32x4 sacc = (f32x4){0.f, 0.f, 0.f, 0.f};
#pragma unroll
        for (int kcp = 0; kcp < 2; ++kcp) {
            const bf16x8 pf = *(const bf16x8*)(Pl + l15 * PSTR2 + kcp * 32 + quad * 8);
            sacc = mfma16(pf, ones, sacc);
#pragma unroll
            for (int db = 0; db < 8; ++db) {
                const bf16x8 vf = *(const bf16x8*)(Vts + (db * 16 + l15) * VSTR + kcp * 32 + quad * 8);
                acc[db] = mfma16(pf, vf, acc[db]);
            }
        }
#pragma unroll
        for (int r = 0; r < 4; ++r) l_[r] = l_[r] * al[r] + sacc[r];
    }
#undef LOAD_TILE

    // ---- write partial slot (wave-private, no merge needed) ----
    const int qt16 = qb * 4 + wv;
    float* slot = Part + (size_t)(qt16 * 8 + chunk) * SLOTD;
    if (l15 == 0) {
#pragma unroll
        for (int r = 0; r < 4; ++r) {
            slot[quad * 4 + r]      = m_[r];
            slot[16 + quad * 4 + r] = l_[r];
        }
    }
    // O as fp16: pair lanes (l15 even/odd -> dims d, d+1) into one dword
    uint* slotO = (uint*)(slot + 32);
#pragma unroll
    for (int d = 0; d < 8; ++d)
#pragma unroll
        for (int r = 0; r < 4; ++r) {
            const float v  = acc[d][r];
            const float vp = __shfl_xor(v, 1);
            if ((l15 & 1) == 0) {
                const int row = quad * 4 + r;
                const uint u = (uint)f2h(v) | ((uint)f2h(vp) << 16);
                slotO[(row * 128 + d * 16 + l15) >> 1] = u;
            }
        }
}

// ---------------------------------------------------------------------------
// Merge <=8 partials per 16-row q-tile, normalize, write output.
// ---------------------------------------------------------------------------
__global__ __launch_bounds__(256)
void flash_merge_kernel(const float* __restrict__ Part, float* __restrict__ Out) {
    __shared__ float Ms[16], Ls[16];
    __shared__ float Sc[8][16];
    const int qt = blockIdx.x;
    const int q0 = qt * 16;
    const int P  = (qt >> 6) + 1;
    const int tid = threadIdx.x;
    const float* base = Part + (size_t)qt * 8 * SLOTD;

    if (tid < 16) {
        float M = -__builtin_inff();
        for (int p = 0; p < P; ++p) M = fmaxf(M, base[p * SLOTD + tid]);
        float L = 0.f;
        for (int p = 0; p < P; ++p)
            L += base[p * SLOTD + 16 + tid] * exp2f(base[p * SLOTD + tid] - M);
        Ms[tid] = M; Ls[tid] = L;
    }
    __syncthreads();
    if (tid < 128) {
        const int p = tid >> 4, row = tid & 15;
        Sc[p][row] = (p < P) ? exp2f(base[p * SLOTD + row] - Ms[row]) : 0.f;
    }
    __syncthreads();

    // 16 rows x 64 dword-pairs (2 fp16 cols each) = 1024 items, 4 per thread
#pragma unroll
    for (int j = tid; j < 1024; j += 256) {
        const int row = j >> 6, c2 = j & 63;
        float o0 = 0.f, o1 = 0.f;
        for (int p = 0; p < P; ++p) {
            const uint u = ((const uint*)(base + p * SLOTD + 32))[row * 64 + c2];
            const float sc = Sc[p][row];
            o0 += (float)__builtin_bit_cast(_Float16, (ushort)(u & 0xFFFF)) * sc;
            o1 += (float)__builtin_bit_cast(_Float16, (ushort)(u >> 16)) * sc;
        }
        const float inv = 1.0f / Ls[row];
        float2 o; o.x = o0 * inv; o.y = o1 * inv;
        *(float2*)(Out + (size_t)(q0 + row) * DK + c2 * 2) = o;
    }
}

extern "C" void kernel_launch(void* const* d_in, const int* in_sizes, int n_in,
                              void* d_out, int out_size, void* d_ws, size_t ws_size,
                              hipStream_t stream) {
    const float* X  = (const float*)d_in[0];
    const float* Wq = (const float*)d_in[1];
    const float* Wk = (const float*)d_in[2];
    const float* Wv = (const float*)d_in[3];
    ushort* ws  = (ushort*)d_ws;
    ushort* Qb  = ws;                          // 8192x128 bf16 (pre-scaled)
    ushort* Kb  = ws + (size_t)S_LEN * DK;     // 8192x128 bf16
    ushort* Vtb = ws + 2 * (size_t)S_LEN * DK; // 128x8192 bf16 (transposed)
    _Float16* Xh = (_Float16*)(ws + 3 * (size_t)S_LEN * DK);  // 8192x1024 fp16
    _Float16* Wh = Xh + (size_t)S_LEN * DM;                   // 384x1024 fp16
    // Partials alias Xh/Wh (dead after proj_gemm): 4096 slots * 4224 B = 16.5 MiB
    float* Part = (float*)Xh;
    float* Out = (float*)d_out;

    convert_kernel<<<1024, 256, 0, stream>>>(X, Wq, Wk, Wv, Xh, Wh);
    proj_gemm_kernel<<<dim3(256, 3), 256, 0, stream>>>(Xh, Wh, Qb, Kb, Vtb);
    flash_partial_kernel<<<576, 256, 0, stream>>>(Qb, Kb, Vtb, Part);
    flash_merge_kernel<<<512, 256, 0, stream>>>(Part, Out);
}